// Round 12
// baseline (91.687 us; speedup 1.0000x reference)
//
#include <hip/hip_runtime.h>
#include <stdint.h>

// DetectionLoss for B=16, N=884736. Output: [cls_pos_loss, cls_neg_loss].
//
// R11 diagnosis: expand ~20us = 205k global hist atomics (1024 lines) +
// dependent scattered mask->pred gathers at 3.4 blocks/CU TLP. R12: histogram
// ELIMINATED. passA publishes exact per-sample candidate count; expand
// computes the predicted 10000th-key cut from cnt (keys uniform on
// [THRESH,2^23)), classifies inline: key>cut+M -> block-reduced loss sum;
// key in +-M window (~1265/sample, 6-sigma margin) -> window buffer; B3 does
// exact in-LDS selection on the window (tie: lowest idx). g_rec/g_x kept only
// for the (dead) exact fallback paths. B2 kernel deleted.

#define BATCH 16
#define NPTS 884736u
#define THRESH_KEY 8266976u    // keys kept: >= this (tail 0.01450)
#define THRESH_W   4232691712u // THRESH_KEY<<9 (compare on raw 32-bit word)
#define RANGE 121632u          // 2^23 - THRESH_KEY
#define KEYMAX 8388607u
#define CAP 13824u             // fallback record cap/sample (mean 12825, 9 sigma)
#define BCAP 64
#define KSEL 10000u
#define WCAP 2048u             // window buffer/sample (expect ~1265, 22 sigma)
#define MARGIN 6000u           // ~6.4 sigma of cut-key uncertainty (~940)
#define EPT 8u
#define NBLK 432u              // passA grid.x; NBLK*2048 = NPTS
#define EGRID 108u             // expand grid.x: 27648 half-words / 256

// hdr line (256B/sample): +0 f32 pos_sum, +4 u32 npos, +8 u32 rec_alloc,
// +12 f32 neg_result, +16 u32 cand_total, +20 u32 n_hi, +24 f32 sum_hi,
// +28 u32 n_win

struct KeyPairs { unsigned k[2 * BATCH]; };

__host__ __device__ __forceinline__ void tf2x32(unsigned k0, unsigned k1,
                                                unsigned x0, unsigned x1,
                                                unsigned& o0, unsigned& o1)
{
  unsigned ks0 = k0, ks1 = k1, ks2 = k0 ^ k1 ^ 0x1BD11BDAu;
  x0 += ks0; x1 += ks1;
#define TF_R(r) { x0 += x1; x1 = __builtin_rotateleft32(x1, r); x1 ^= x0; }
  TF_R(13) TF_R(15) TF_R(26) TF_R(6)
  x0 += ks1; x1 += ks2 + 1u;
  TF_R(17) TF_R(29) TF_R(16) TF_R(24)
  x0 += ks2; x1 += ks0 + 2u;
  TF_R(13) TF_R(15) TF_R(26) TF_R(6)
  x0 += ks0; x1 += ks1 + 3u;
  TF_R(17) TF_R(29) TF_R(16) TF_R(24)
  x0 += ks1; x1 += ks2 + 4u;
  TF_R(13) TF_R(15) TF_R(26) TF_R(6)
  x0 += ks2; x1 += ks0 + 5u;
#undef TF_R
  o0 = x0; o1 = x1;
}

__device__ __forceinline__ float lossf(float x, float t, float m)
{
  float e  = __expf(-x);
  float p  = __fdividef(1.0f, 1.0f + e);
  p = fminf(fmaxf(p, 1e-4f), 1.0f - 1e-4f);
  bool is_pos = (t == 1.0f);
  float alpha = is_pos ? 0.75f : 0.25f;
  float pw = is_pos ? (1.0f - p) : p;
  float soft = __logf(1.0f + __expf(-fabsf(x)));
  float bce = fmaxf(x, 0.0f) - x * t + soft;
  float L = (m == 0.0f) ? alpha * pw * pw * bce : 0.0f;
  if (is_pos && p < 0.8f) L *= 4.0f;
  if (!is_pos && p > 0.5f)
    L *= 1.5f + fminf(fmaxf((p - 0.5f) * 5.0f, 0.0f), 1.0f) * 0.5f;
  return L;
}

__global__ __launch_bounds__(256) void passA(
    const float* __restrict__ pred, const float* __restrict__ target,
    const float* __restrict__ mask, char* __restrict__ hdr,
    unsigned long long* __restrict__ cand_mask, KeyPairs kp)
{
  const int b = blockIdx.y;
  const int tid = threadIdx.x;
  const unsigned i0 = (blockIdx.x * 256u + tid) * EPT;
  const size_t off = (size_t)b * NPTS + i0;
  const unsigned k0 = kp.k[2 * b], k1 = kp.k[2 * b + 1];
  char* line = hdr + (size_t)b * 256;

  float4 t4a = *reinterpret_cast<const float4*>(target + off);
  float4 t4b = *reinterpret_cast<const float4*>(target + off + 4);
  float tv[8] = { t4a.x, t4a.y, t4a.z, t4a.w, t4b.x, t4b.y, t4b.z, t4b.w };

  unsigned kw[8];
#pragma unroll
  for (int r = 0; r < 8; ++r) {
    unsigned o0, o1;
    tf2x32(k0, k1, 0u, i0 + (unsigned)r, o0, o1);   // partitionable: (0, i)
    kw[r] = o0 ^ o1;                                 // raw word; key = kw>>9
  }

  unsigned long long B0 = __ballot((tv[0] == 0.0f) && (kw[0] >= THRESH_W));
  unsigned long long B1 = __ballot((tv[1] == 0.0f) && (kw[1] >= THRESH_W));
  unsigned long long B2 = __ballot((tv[2] == 0.0f) && (kw[2] >= THRESH_W));
  unsigned long long B3 = __ballot((tv[3] == 0.0f) && (kw[3] >= THRESH_W));
  unsigned long long B4 = __ballot((tv[4] == 0.0f) && (kw[4] >= THRESH_W));
  unsigned long long B5 = __ballot((tv[5] == 0.0f) && (kw[5] >= THRESH_W));
  unsigned long long B6 = __ballot((tv[6] == 0.0f) && (kw[6] >= THRESH_W));
  unsigned long long B7 = __ballot((tv[7] == 0.0f) && (kw[7] >= THRESH_W));

  unsigned posm = 0;
#pragma unroll
  for (int r = 0; r < 8; ++r)
    if (tv[r] == 1.0f) posm |= (1u << r);

  const int wv = tid >> 6, lane = tid & 63;
  __shared__ unsigned s_wcnt[4];
  if (lane == 0) {
    unsigned long long* dst =
        cand_mask + ((size_t)((b * (int)NBLK + blockIdx.x) * 4 + wv)) * 8;
    reinterpret_cast<ulonglong2*>(dst)[0] = ulonglong2{B0, B1};
    reinterpret_cast<ulonglong2*>(dst)[1] = ulonglong2{B2, B3};
    reinterpret_cast<ulonglong2*>(dst)[2] = ulonglong2{B4, B5};
    reinterpret_cast<ulonglong2*>(dst)[3] = ulonglong2{B6, B7};
    s_wcnt[wv] = (unsigned)(__popcll(B0) + __popcll(B1) + __popcll(B2) +
                            __popcll(B3) + __popcll(B4) + __popcll(B5) +
                            __popcll(B6) + __popcll(B7));
  }
  __syncthreads();
  if (tid == 0) {
    unsigned tot = s_wcnt[0] + s_wcnt[1] + s_wcnt[2] + s_wcnt[3];
    if (tot) atomicAdd((unsigned*)(line + 16), tot);
  }

  if (posm) {   // rare (P(thread)~0.4%)
    float psum = 0.0f;
#pragma unroll
    for (int r = 0; r < 8; ++r) {
      if (posm & (1u << r)) {
        float x = pred[off + r];
        float m = mask[off + r];
        psum += lossf(x, 1.0f, m);
      }
    }
    atomicAdd((float*)(line + 0), psum);
    atomicAdd((unsigned*)(line + 4), __popc(posm));
  }
}

// expand: 256 thr/block, one 32-bit half-word/thread (27648/sample -> 108 blk).
// Inline classification: hi -> block-reduced sum; window -> wbuf; all -> g_rec.
__global__ __launch_bounds__(256) void expand(
    const float* __restrict__ pred, const float* __restrict__ mask,
    char* __restrict__ hdr, const unsigned* __restrict__ cm32,
    unsigned* __restrict__ wkey, unsigned* __restrict__ widx,
    float* __restrict__ wloss, unsigned long long* __restrict__ g_rec,
    float* __restrict__ g_x, unsigned cap, KeyPairs kp)
{
  const int b = blockIdx.y;
  const int tid = threadIdx.x;
  const int lane = tid & 63, w = tid >> 6;
  char* line = hdr + (size_t)b * 256;

  const unsigned cnt_total = *(const unsigned*)(line + 16);
  const bool take_all = (cnt_total <= KSEL);
  unsigned Thi = 0, Tlo = 0;
  if (!take_all) {
    unsigned cut = 8388608u - (unsigned)(((unsigned long long)KSEL * RANGE) / cnt_total);
    Thi = cut + MARGIN; if (Thi > KEYMAX) Thi = KEYMAX;
    Tlo = (cut > THRESH_KEY + MARGIN) ? (cut - MARGIN) : THRESH_KEY;
  }

  const unsigned h = blockIdx.x * 256u + (unsigned)tid;   // half-word index
  const unsigned wi = h >> 1, half = h & 1u;
  const unsigned blk = wi >> 5, q = wi & 31u, wv_ = q >> 3, r = q & 7u;
  unsigned cw = cm32[(size_t)b * (NBLK * 64u) + h];       // 27648 u32/sample
  const unsigned ibase = blk * 2048u + wv_ * 512u + half * 256u + r;

  unsigned cnt = (unsigned)__popc(cw);
  unsigned pfx = cnt;
#pragma unroll
  for (int s = 1; s < 64; s <<= 1) {
    unsigned u = __shfl_up(pfx, s, 64);
    if (lane >= s) pfx += u;
  }
  __shared__ unsigned wt[4];
  __shared__ unsigned s_gb;
  if (lane == 63) wt[w] = pfx;
  __syncthreads();
  if (tid == 0) {
    unsigned tot = wt[0] + wt[1] + wt[2] + wt[3];
    s_gb = tot ? atomicAdd((unsigned*)(line + 8), tot) : 0u;
  }
  __syncthreads();
  unsigned woff = 0;
#pragma unroll
  for (int qq = 0; qq < 4; ++qq) if (qq < w) woff += wt[qq];
  unsigned base = s_gb + woff + (pfx - cnt);

  const unsigned k0 = kp.k[2 * b], k1 = kp.k[2 * b + 1];
  const size_t sbase = (size_t)b * NPTS;
  float hi_sum = 0.0f;
  unsigned hi_n = 0, j = 0;
  while (cw) {
    int l = __ffs(cw) - 1;
    cw &= cw - 1u;
    unsigned i = ibase + (unsigned)l * 8u;
    unsigned o0, o1;
    tf2x32(k0, k1, 0u, i, o0, o1);
    unsigned kk = (o0 ^ o1) >> 9;
    float xv = pred[sbase + i];           // independent loads (issue parallel)
    float mv = mask[sbase + i];
    float x = (mv == 0.0f) ? xv : -1000.0f;  // mask -> lossf()==0 exactly
    unsigned p = base + j; ++j;
    if (p < cap) {
      size_t o = (size_t)b * cap + p;
      g_rec[o] = ((unsigned long long)kk << 20) | i;
      g_x[o]   = x;
    }
    if (take_all || kk > Thi) {
      hi_sum += lossf(x, 0.0f, 0.0f); hi_n++;
    } else if (kk >= Tlo) {
      unsigned wp = atomicAdd((unsigned*)(line + 28), 1u);
      if (wp < WCAP) {
        wkey[b * WCAP + wp] = kk;
        widx[b * WCAP + wp] = i;
        wloss[b * WCAP + wp] = lossf(x, 0.0f, 0.0f);
      }
    }
  }
  __shared__ float redf[256];
  __shared__ unsigned redu[256];
  redf[tid] = hi_sum; redu[tid] = hi_n;
  __syncthreads();
  for (int st = 128; st > 0; st >>= 1) {
    if (tid < st) { redf[tid] += redf[tid + st]; redu[tid] += redu[tid + st]; }
    __syncthreads();
  }
  if (tid == 0 && redu[0]) {
    atomicAdd((float*)(line + 24), redf[0]);
    atomicAdd((unsigned*)(line + 20), redu[0]);
  }
}

// B3: exact selection. Normal path: in-LDS window search (tie: lowest idx).
// Fallback (dead): exact key search / loss-top-k over g_rec/g_x.
__global__ __launch_bounds__(256) void passB3(
    char* __restrict__ hdr, const unsigned* __restrict__ wkey,
    const unsigned* __restrict__ widx, const float* __restrict__ wloss,
    const unsigned long long* __restrict__ g_rec,
    const float* __restrict__ g_x, unsigned cap)
{
  const int b = blockIdx.x;
  const int tid = threadIdx.x;
  char* line = hdr + (size_t)b * 256;

  __shared__ unsigned skey[WCAP];
  __shared__ unsigned sidx[WCAP];
  __shared__ float    sls[WCAP];
  __shared__ unsigned redu[256];
  __shared__ float    redf[256];
  __shared__ unsigned s_eqc, s_u1;
  __shared__ unsigned s_eqi[BCAP];
  __shared__ float    s_eql[BCAP];
  __shared__ float    s_res;

  const unsigned cnt_total = *(const unsigned*)(line + 16);
  const unsigned n_hi      = *(const unsigned*)(line + 20);
  const float    sum_hi    = *(const float*)(line + 24);
  const unsigned n_win     = *(const unsigned*)(line + 28);
  const unsigned npos      = *(const unsigned*)(line + 4);
  const bool take_all = (cnt_total <= KSEL);
  const unsigned nsel = take_all ? cnt_total : KSEL;
  const unsigned k = (npos > 0u) ? ((100u * npos < KSEL) ? 100u * npos : KSEL) : 100u;

  unsigned Thi = 0, Tlo = 0;
  if (!take_all) {
    unsigned cut = 8388608u - (unsigned)(((unsigned long long)KSEL * RANGE) / cnt_total);
    Thi = cut + MARGIN; if (Thi > KEYMAX) Thi = KEYMAX;
    Tlo = (cut > THRESH_KEY + MARGIN) ? (cut - MARGIN) : THRESH_KEY;
  }
  const bool window_ok = !take_all && (n_win <= WCAP) && (n_hi <= KSEL) &&
                         (KSEL <= n_hi + n_win);

  float result = 0.0f;
  bool done = false;

  if (take_all && k >= nsel) { result = sum_hi; done = true; }
  else if (window_ok && k >= KSEL) {
    const unsigned nw = n_win;
    for (unsigned e = tid; e < nw; e += 256) {
      skey[e] = wkey[b * WCAP + e];
      sidx[e] = widx[b * WCAP + e];
      sls[e]  = wloss[b * WCAP + e];
    }
    __syncthreads();
    unsigned need = KSEL - n_hi;
    if (need == 0) { result = sum_hi; done = true; }
    else {
      auto cGe = [&](unsigned v) -> unsigned {
        unsigned c = 0;
        for (unsigned e = tid; e < nw; e += 256) c += (skey[e] >= v) ? 1u : 0u;
        redu[tid] = c; __syncthreads();
        for (int s = 128; s > 0; s >>= 1) { if (tid < s) redu[tid] += redu[tid + s]; __syncthreads(); }
        unsigned rr = redu[0]; __syncthreads(); return rr;
      };
      unsigned lo = Tlo, hi = Thi;
      while (lo < hi) {
        unsigned mid = lo + (hi - lo + 1u) / 2u;
        if (cGe(mid) >= need) lo = mid; else hi = mid - 1u;
      }
      unsigned V = lo;
      unsigned c_gt = cGe(V + 1u);
      unsigned m = need - c_gt;
      float s = 0.0f;
      for (unsigned e = tid; e < nw; e += 256) if (skey[e] > V) s += sls[e];
      redf[tid] = s; __syncthreads();
      for (int st = 128; st > 0; st >>= 1) { if (tid < st) redf[tid] += redf[tid + st]; __syncthreads(); }
      float sum_gt = redf[0];
      __syncthreads();
      if (tid == 0) s_eqc = 0;
      __syncthreads();
      for (unsigned e = tid; e < nw; e += 256) {
        if (skey[e] == V) {
          unsigned p = atomicAdd(&s_eqc, 1u);
          if (p < BCAP) { s_eqi[p] = sidx[e]; s_eql[p] = sls[e]; }
        }
      }
      __syncthreads();
      if (tid == 0) {
        unsigned ne = s_eqc; if (ne > BCAP) ne = BCAP;
        float es = 0.0f;
        for (unsigned a = 0; a < m && a < ne; ++a) {   // idx asc (LDS only)
          unsigned best = a;
          for (unsigned qq = a + 1; qq < ne; ++qq)
            if (s_eqi[qq] < s_eqi[best]) best = qq;
          unsigned ti = s_eqi[a]; s_eqi[a] = s_eqi[best]; s_eqi[best] = ti;
          float tl = s_eql[a]; s_eql[a] = s_eql[best]; s_eql[best] = tl;
          es += s_eql[a];
        }
        s_res = sum_hi + sum_gt + es;
      }
      __syncthreads();
      result = s_res; done = true;
    }
  }

  if (!done) {   // exact fallback over g_rec/g_x (dead for this data)
    const unsigned cntr = cnt_total < cap ? cnt_total : cap;
    const unsigned long long* Gr = g_rec + (size_t)b * cap;
    const float* Gx = g_x + (size_t)b * cap;
    unsigned V = 0, idxcut = 0xffffffffu;
    float eq_sum = 0.0f;
    auto cKeyGe = [&](unsigned v) -> unsigned {
      unsigned c = 0;
      for (unsigned e = tid; e < cntr; e += 256)
        c += ((unsigned)(Gr[e] >> 20) >= v) ? 1u : 0u;
      redu[tid] = c; __syncthreads();
      for (int s = 128; s > 0; s >>= 1) { if (tid < s) redu[tid] += redu[tid + s]; __syncthreads(); }
      unsigned rr = redu[0]; __syncthreads(); return rr;
    };
    if (!take_all) {
      unsigned lo = THRESH_KEY, hi = KEYMAX;
      while (lo < hi) {
        unsigned mid = lo + (hi - lo + 1u) / 2u;
        if (cKeyGe(mid) >= KSEL) lo = mid; else hi = mid - 1u;
      }
      V = lo;
      unsigned c_gt = cKeyGe(V + 1u);
      unsigned needq = KSEL - c_gt;
      if (tid == 0) s_eqc = 0;
      __syncthreads();
      for (unsigned e = tid; e < cntr; e += 256) {
        unsigned long long rc = Gr[e];
        if ((unsigned)(rc >> 20) == V) {
          unsigned p = atomicAdd(&s_eqc, 1u);
          if (p < BCAP) { s_eqi[p] = (unsigned)(rc & 0xFFFFFu); s_eql[p] = lossf(Gx[e], 0.0f, 0.0f); }
        }
      }
      __syncthreads();
      if (tid == 0) {
        unsigned ne = s_eqc; if (ne > BCAP) ne = BCAP;
        unsigned mm = needq < ne ? needq : ne;
        float es = 0.0f; unsigned ic = 0xffffffffu;
        for (unsigned a = 0; a < mm; ++a) {
          unsigned best = a;
          for (unsigned qq = a + 1; qq < ne; ++qq)
            if (s_eqi[qq] < s_eqi[best]) best = qq;
          unsigned ti = s_eqi[a]; s_eqi[a] = s_eqi[best]; s_eqi[best] = ti;
          float tl = s_eql[a]; s_eql[a] = s_eql[best]; s_eql[best] = tl;
          es += s_eql[a];
        }
        if (mm > 0) ic = s_eqi[mm - 1];
        s_res = es; s_u1 = ic;
      }
      __syncthreads();
      eq_sum = s_res; idxcut = s_u1;
      __syncthreads();
    }
    auto selp = [&](unsigned e) -> bool {
      if (take_all) return true;
      unsigned long long rc = Gr[e];
      unsigned kk = (unsigned)(rc >> 20);
      if (kk > V) return true;
      if (kk < V) return false;
      return (unsigned)(rc & 0xFFFFFu) <= idxcut;
    };
    if (k >= nsel) {
      float s = 0.0f;
      for (unsigned e = tid; e < cntr; e += 256) {
        if (take_all) s += lossf(Gx[e], 0.0f, 0.0f);
        else if ((unsigned)(Gr[e] >> 20) > V) s += lossf(Gx[e], 0.0f, 0.0f);
      }
      redf[tid] = s; __syncthreads();
      for (int st = 128; st > 0; st >>= 1) { if (tid < st) redf[tid] += redf[tid + st]; __syncthreads(); }
      result = redf[0] + (take_all ? 0.0f : eq_sum);
      __syncthreads();
    } else {
      auto cLossGe = [&](unsigned wv) -> unsigned {
        unsigned c = 0;
        for (unsigned e = tid; e < cntr; e += 256)
          if (selp(e) && __float_as_uint(lossf(Gx[e], 0.0f, 0.0f)) >= wv) c++;
        redu[tid] = c; __syncthreads();
        for (int s = 128; s > 0; s >>= 1) { if (tid < s) redu[tid] += redu[tid + s]; __syncthreads(); }
        unsigned rr = redu[0]; __syncthreads(); return rr;
      };
      unsigned lo = 0u, hi = 0x7f7fffffu;
      while (lo < hi) {
        unsigned mid = lo + (hi - lo + 1u) / 2u;
        if (cLossGe(mid) >= k) lo = mid; else hi = mid - 1u;
      }
      unsigned cgt = cLossGe(lo + 1u);
      float s2 = 0.0f;
      for (unsigned e = tid; e < cntr; e += 256) {
        float L = lossf(Gx[e], 0.0f, 0.0f);
        if (selp(e) && __float_as_uint(L) > lo) s2 += L;
      }
      redf[tid] = s2; __syncthreads();
      for (int st = 128; st > 0; st >>= 1) { if (tid < st) redf[tid] += redf[tid + st]; __syncthreads(); }
      result = redf[0] + (float)(k - cgt) * __uint_as_float(lo);
      __syncthreads();
    }
  }

  if (tid == 0) *(float*)(line + 12) = result;
}

__global__ void passC(const char* __restrict__ hdr, float* __restrict__ out)
{
  const int lane = threadIdx.x;
  float ps = 0.0f, ns = 0.0f;
  if (lane < BATCH) {
    const char* line = hdr + (size_t)lane * 256;
    unsigned np = *(const unsigned*)(line + 4);
    float denom = (np > 0u) ? fmaxf((float)np, 1.0f) : 1.0f;
    ps = (*(const float*)(line + 0)) / denom;
    ns = (*(const float*)(line + 12)) / denom;
  }
#pragma unroll
  for (int s = 8; s > 0; s >>= 1) {
    ps += __shfl_down(ps, s, 64);
    ns += __shfl_down(ns, s, 64);
  }
  if (lane == 0 && blockIdx.x == 0) {
    out[0] = ps / (float)BATCH;
    out[1] = ns / (float)BATCH;
  }
}

extern "C" void kernel_launch(void* const* d_in, const int* in_sizes, int n_in,
                              void* d_out, int out_size, void* d_ws, size_t ws_size,
                              hipStream_t stream)
{
  const float* pred   = (const float*)d_in[0];
  const float* target = (const float*)d_in[1];
  const float* mask   = (const float*)d_in[2];
  float* out = (float*)d_out;

  const size_t MASK_BYTES = (size_t)BATCH * NBLK * 32 * 8;          // 1,769,472
  const size_t WBUF_BYTES = 3 * (size_t)BATCH * WCAP * 4;           //   393,216
  const size_t FIXED = 4096 + MASK_BYTES + WBUF_BYTES;              // 2,166,784
  size_t avail = (ws_size > FIXED) ? (ws_size - FIXED) : 0;
  unsigned cap = (unsigned)(avail / ((size_t)BATCH * 12));
  if (cap > CAP) cap = CAP;
  if (cap == 0 || out_size < 2) {
    hipMemsetAsync(d_out, 0, sizeof(float) * (out_size > 0 ? out_size : 1), stream);
    return;
  }

  char* ws = (char*)d_ws;
  char*     hdr   = ws;
  unsigned long long* cand_mask = (unsigned long long*)(ws + 4096);
  unsigned* wkey  = (unsigned*)(ws + 4096 + MASK_BYTES);
  unsigned* widx  = wkey + (size_t)BATCH * WCAP;
  float*    wloss = (float*)(widx + (size_t)BATCH * WCAP);
  unsigned long long* g_rec = (unsigned long long*)(ws + FIXED);
  float*    g_x   = (float*)(ws + FIXED + (size_t)BATCH * cap * 8);

  KeyPairs kp;
  for (unsigned b = 0; b < BATCH; ++b) {
    unsigned o0, o1;
    tf2x32(0u, 42u, 0u, b, o0, o1);
    kp.k[2 * b] = o0; kp.k[2 * b + 1] = o1;
  }

  hipMemsetAsync(hdr, 0, 4096, stream);

  passA<<<dim3(NBLK, BATCH), 256, 0, stream>>>(pred, target, mask, hdr,
                                               cand_mask, kp);
  expand<<<dim3(EGRID, BATCH), 256, 0, stream>>>(pred, mask, hdr,
                                                 (const unsigned*)cand_mask,
                                                 wkey, widx, wloss,
                                                 g_rec, g_x, cap, kp);
  passB3<<<BATCH, 256, 0, stream>>>(hdr, wkey, widx, wloss, g_rec, g_x, cap);
  passC<<<1, 64, 0, stream>>>(hdr, out);
}

// Round 14
// 88.693 us; speedup vs baseline: 1.0338x; 1.0338x over previous
//
#include <hip/hip_runtime.h>
#include <stdint.h>

// DetectionLoss for B=16, N=884736. Output: [cls_pos_loss, cls_neg_loss].
//
// R12 lesson: the separate candidate-expansion pass costs ~20us no matter its
// internals. R13/R14: expansion DELETED. Fixed compile-time key thresholds
// (cut0 -+ 8000, 8+ sigma) let passA classify candidates inline:
//   key > THI          -> lossf, block-reduced sum (n_hi ~9157)
//   TLO <= key <= THI  -> window append via LDS staging (~1687/sample)
//   else               -> counted only
// Select (16 blocks): exact top-(KSEL-n_hi) of window in LDS, tie = lowest
// idx (XLA top_k semantics, verified bit-exact in R6-R12); rescan-based
// exact fallback for dead branches (take_all / npos<100 / window miss).
// Counters live on separate 64B sub-lines (512B/sample) to avoid same-line
// atomic serialization (R3 lesson).
// (R14 = R13 resubmitted; round 13 died to infra before running.)

#define BATCH 16
#define NPTS 884736u
#define THRESH_KEY 8266976u    // candidate keys >= this (tail 0.01450)
#define THRESH_W   4232691712u // THRESH_KEY<<9 (raw-word compare)
#define KEYMAX 8388607u
#define KSEL 10000u
// cut0 = 2^23 - KSEL*121632/12822 ~= 8293746 ; margin 8000 ~= 8.5 sigma
#define TLO 8285746u
#define THI 8301746u
#define TLO_W 4242301952u      // TLO<<9
#define HI_W  4250494464u      // (THI+1)<<9 : kw>=HI_W <=> key>THI
#define WCAP 3072u             // global window cap/sample (E~1687, sd 41)
#define LCAP 64                // per-block LDS window staging (E~3.9)
#define BCAP 64
#define NBLK 432u              // mono grid.x ; 432*2048 = NPTS
#define EPT 8u
#define HDRB 512               // per-sample header stride

// hdr line (512B/sample): +0 f32 pos_sum | +4 u32 npos   (64B line A)
//   +64 u32 cand_total (line B) | +128 u32 n_hi, +132 f32 sum_hi (line C)
//   +192 u32 n_win, +196 u32 fail (line D) | +256 f32 neg_result (line E)

struct KeyPairs { unsigned k[2 * BATCH]; };

__host__ __device__ __forceinline__ void tf2x32(unsigned k0, unsigned k1,
                                                unsigned x0, unsigned x1,
                                                unsigned& o0, unsigned& o1)
{
  unsigned ks0 = k0, ks1 = k1, ks2 = k0 ^ k1 ^ 0x1BD11BDAu;
  x0 += ks0; x1 += ks1;
#define TF_R(r) { x0 += x1; x1 = __builtin_rotateleft32(x1, r); x1 ^= x0; }
  TF_R(13) TF_R(15) TF_R(26) TF_R(6)
  x0 += ks1; x1 += ks2 + 1u;
  TF_R(17) TF_R(29) TF_R(16) TF_R(24)
  x0 += ks2; x1 += ks0 + 2u;
  TF_R(13) TF_R(15) TF_R(26) TF_R(6)
  x0 += ks0; x1 += ks1 + 3u;
  TF_R(17) TF_R(29) TF_R(16) TF_R(24)
  x0 += ks1; x1 += ks2 + 4u;
  TF_R(13) TF_R(15) TF_R(26) TF_R(6)
  x0 += ks2; x1 += ks0 + 5u;
#undef TF_R
  o0 = x0; o1 = x1;
}

__device__ __forceinline__ float lossf(float x, float t, float m)
{
  float e  = __expf(-x);
  float p  = __fdividef(1.0f, 1.0f + e);
  p = fminf(fmaxf(p, 1e-4f), 1.0f - 1e-4f);
  bool is_pos = (t == 1.0f);
  float alpha = is_pos ? 0.75f : 0.25f;
  float pw = is_pos ? (1.0f - p) : p;
  float soft = __logf(1.0f + __expf(-fabsf(x)));
  float bce = fmaxf(x, 0.0f) - x * t + soft;
  float L = (m == 0.0f) ? alpha * pw * pw * bce : 0.0f;
  if (is_pos && p < 0.8f) L *= 4.0f;
  if (!is_pos && p > 0.5f)
    L *= 1.5f + fminf(fmaxf((p - 0.5f) * 5.0f, 0.0f), 1.0f) * 0.5f;
  return L;
}

__global__ __launch_bounds__(256) void mono(
    const float* __restrict__ pred, const float* __restrict__ target,
    const float* __restrict__ mask, char* __restrict__ hdr,
    unsigned* __restrict__ wkey, unsigned* __restrict__ widx,
    float* __restrict__ wloss, KeyPairs kp)
{
  const int b = blockIdx.y;
  const int tid = threadIdx.x;
  const unsigned i0 = (blockIdx.x * 256u + tid) * EPT;
  const size_t off = (size_t)b * NPTS + i0;
  const unsigned k0 = kp.k[2 * b], k1 = kp.k[2 * b + 1];
  char* line = hdr + (size_t)b * HDRB;

  __shared__ unsigned s_wn, s_base;
  __shared__ unsigned s_wk[LCAP], s_wi[LCAP];
  __shared__ float    s_wl[LCAP];
  __shared__ unsigned redu[256], redv[256];
  __shared__ float    redh[256], redp[256];

  if (tid == 0) s_wn = 0;
  __syncthreads();

  float4 t4a = *reinterpret_cast<const float4*>(target + off);
  float4 t4b = *reinterpret_cast<const float4*>(target + off + 4);
  float tv[8] = { t4a.x, t4a.y, t4a.z, t4a.w, t4b.x, t4b.y, t4b.z, t4b.w };

  unsigned kw[8];
#pragma unroll
  for (int r = 0; r < 8; ++r) {
    unsigned o0, o1;
    tf2x32(k0, k1, 0u, i0 + (unsigned)r, o0, o1);   // partitionable: (0, i)
    kw[r] = o0 ^ o1;                                 // raw word; key = kw>>9
  }

  unsigned candm = 0, posm = 0, him = 0, winm = 0;
#pragma unroll
  for (int r = 0; r < 8; ++r) {
    bool c  = (tv[r] == 0.0f) && (kw[r] >= THRESH_W);
    bool hi = c && (kw[r] >= HI_W);
    bool wn = c && !hi && (kw[r] >= TLO_W);
    candm |= (unsigned)c  << r;
    him   |= (unsigned)hi << r;
    winm  |= (unsigned)wn << r;
    posm  |= (unsigned)(tv[r] == 1.0f) << r;
  }

  float psum = 0.0f, hsum = 0.0f;
  const unsigned flags = him | winm | posm;
  if (flags) {
#pragma unroll
    for (int r = 0; r < 8; ++r) {
      if ((flags >> r) & 1u) {
        float x = pred[off + r];
        float m = mask[off + r];
        float L = lossf(x, tv[r], m);          // t=tv handles pos & neg
        if ((posm >> r) & 1u) psum += L;
        else if ((him >> r) & 1u) hsum += L;
        else {                                  // window
          unsigned p = atomicAdd(&s_wn, 1u);
          if (p < LCAP) { s_wk[p] = kw[r] >> 9; s_wi[p] = i0 + (unsigned)r; s_wl[p] = L; }
        }
      }
    }
  }

  // block reduce: cand|hi packed (each <=2048), pos separate
  redu[tid] = (unsigned)__popc(candm) | ((unsigned)__popc(him) << 16);
  redv[tid] = (unsigned)__popc(posm);
  redh[tid] = hsum; redp[tid] = psum;
  __syncthreads();
  for (int s = 128; s > 0; s >>= 1) {
    if (tid < s) {
      redu[tid] += redu[tid + s]; redv[tid] += redv[tid + s];
      redh[tid] += redh[tid + s]; redp[tid] += redp[tid + s];
    }
    __syncthreads();
  }
  if (tid == 0) {
    unsigned c = redu[0] & 0xFFFFu, h = redu[0] >> 16, p = redv[0];
    if (c) atomicAdd((unsigned*)(line + 64), c);
    if (h) { atomicAdd((unsigned*)(line + 128), h); atomicAdd((float*)(line + 132), redh[0]); }
    if (p) { atomicAdd((unsigned*)(line + 4), p); atomicAdd((float*)(line + 0), redp[0]); }
    unsigned wn = s_wn;
    if (wn > LCAP) { atomicOr((unsigned*)(line + 196), 1u); wn = LCAP; }
    s_base = wn ? atomicAdd((unsigned*)(line + 192), wn) : 0u;
    s_wn = wn;
  }
  __syncthreads();
  unsigned wn = s_wn, gb = s_base;
  for (unsigned e = tid; e < wn; e += 256) {
    unsigned g = gb + e;
    if (g < WCAP) {
      wkey[b * WCAP + g] = s_wk[e];
      widx[b * WCAP + g] = s_wi[e];
      wloss[b * WCAP + g] = s_wl[e];
    }
  }
}

// select: 16 blocks. Normal: exact window selection in LDS. Fallback (dead):
// exact via full-input rescans.
__global__ __launch_bounds__(256) void select_k(
    const float* __restrict__ pred, const float* __restrict__ target,
    const float* __restrict__ mask, char* __restrict__ hdr,
    const unsigned* __restrict__ wkey, const unsigned* __restrict__ widx,
    const float* __restrict__ wloss, KeyPairs kp)
{
  const int b = blockIdx.x;
  const int tid = threadIdx.x;
  char* line = hdr + (size_t)b * HDRB;

  __shared__ unsigned skey[WCAP], sidx[WCAP];
  __shared__ float    sls[WCAP];
  __shared__ unsigned redu[256];
  __shared__ float    redf[256];
  __shared__ unsigned s_eqc, s_u1;
  __shared__ unsigned s_eqi[BCAP];
  __shared__ float    s_eql[BCAP];
  __shared__ float    s_f;

  const unsigned cnt    = *(const unsigned*)(line + 64);
  const unsigned n_hi   = *(const unsigned*)(line + 128);
  const float    sum_hi = *(const float*)(line + 132);
  const unsigned n_win  = *(const unsigned*)(line + 192);
  const unsigned fail   = *(const unsigned*)(line + 196);
  const unsigned npos   = *(const unsigned*)(line + 4);
  const bool take_all = (cnt <= KSEL);
  const unsigned nsel = take_all ? cnt : KSEL;
  const unsigned k = (npos > 0u) ? ((100u * npos < KSEL) ? 100u * npos : KSEL) : 100u;
  const bool bad = fail || take_all || (n_hi > KSEL) ||
                   (n_hi + n_win < KSEL) || (n_win > WCAP) || (k < nsel);

  auto redSumU = [&](unsigned v) -> unsigned {
    redu[tid] = v; __syncthreads();
    for (int s = 128; s > 0; s >>= 1) { if (tid < s) redu[tid] += redu[tid + s]; __syncthreads(); }
    unsigned r = redu[0]; __syncthreads(); return r;
  };
  auto redSumF = [&](float v) -> float {
    redf[tid] = v; __syncthreads();
    for (int s = 128; s > 0; s >>= 1) { if (tid < s) redf[tid] += redf[tid + s]; __syncthreads(); }
    float r = redf[0]; __syncthreads(); return r;
  };

  float res = 0.0f;

  if (!bad) {
    const unsigned nw = n_win;
    for (unsigned e = tid; e < nw; e += 256) {
      skey[e] = wkey[b * WCAP + e];
      sidx[e] = widx[b * WCAP + e];
      sls[e]  = wloss[b * WCAP + e];
    }
    __syncthreads();
    const unsigned need = KSEL - n_hi;
    if (need == 0) res = sum_hi;
    else {
      auto cGe = [&](unsigned v) -> unsigned {
        unsigned c = 0;
        for (unsigned e = tid; e < nw; e += 256) c += (skey[e] >= v) ? 1u : 0u;
        return redSumU(c);
      };
      unsigned lo = TLO, hi = THI;                 // cGe(TLO)=nw>=need
      while (lo < hi) {
        unsigned mid = lo + (hi - lo + 1u) / 2u;
        if (cGe(mid) >= need) lo = mid; else hi = mid - 1u;
      }
      const unsigned V = lo;
      const unsigned c_gt = cGe(V + 1u);
      const unsigned m = need - c_gt;
      float s = 0.0f;
      for (unsigned e = tid; e < nw; e += 256) if (skey[e] > V) s += sls[e];
      float sum_gt = redSumF(s);
      if (tid == 0) s_eqc = 0;
      __syncthreads();
      for (unsigned e = tid; e < nw; e += 256) {
        if (skey[e] == V) {
          unsigned p = atomicAdd(&s_eqc, 1u);
          if (p < BCAP) { s_eqi[p] = sidx[e]; s_eql[p] = sls[e]; }
        }
      }
      __syncthreads();
      if (tid == 0) {
        unsigned ne = s_eqc; if (ne > BCAP) ne = BCAP;
        unsigned mm = (m < ne) ? m : ne;
        float es = 0.0f;
        for (unsigned a = 0; a < mm; ++a) {        // idx asc (LDS only)
          unsigned best = a;
          for (unsigned q = a + 1; q < ne; ++q)
            if (s_eqi[q] < s_eqi[best]) best = q;
          unsigned ti = s_eqi[a]; s_eqi[a] = s_eqi[best]; s_eqi[best] = ti;
          float tl = s_eql[a]; s_eql[a] = s_eql[best]; s_eql[best] = tl;
          es += s_eql[a];
        }
        s_f = sum_hi + sum_gt + es;
      }
      __syncthreads();
      res = s_f;
    }
  } else {
    // ---- exact fallback via full rescans (dead for this data) ----
    const float* T = target + (size_t)b * NPTS;
    const float* P = pred   + (size_t)b * NPTS;
    const float* M = mask   + (size_t)b * NPTS;
    const unsigned k0 = kp.k[2 * b], k1 = kp.k[2 * b + 1];
    auto keyOf = [&](unsigned i) -> unsigned {
      unsigned o0, o1; tf2x32(k0, k1, 0u, i, o0, o1); return (o0 ^ o1) >> 9;
    };
    auto cKeyGe = [&](unsigned v) -> unsigned {
      unsigned c = 0;
      for (unsigned i = tid; i < NPTS; i += 256)
        if (T[i] == 0.0f && keyOf(i) >= v) c++;
      return redSumU(c);
    };
    unsigned V = 0, idxcut = 0xffffffffu; float eq_sum = 0.0f;
    if (!take_all) {
      unsigned lo = THRESH_KEY, hi = KEYMAX;
      while (lo < hi) {
        unsigned mid = lo + (hi - lo + 1u) / 2u;
        if (cKeyGe(mid) >= KSEL) lo = mid; else hi = mid - 1u;
      }
      V = lo;
      unsigned c_gt = cKeyGe(V + 1u);
      unsigned needq = KSEL - c_gt;
      if (tid == 0) s_eqc = 0;
      __syncthreads();
      for (unsigned i = tid; i < NPTS; i += 256)
        if (T[i] == 0.0f && keyOf(i) == V) {
          unsigned p = atomicAdd(&s_eqc, 1u);
          if (p < BCAP) s_eqi[p] = i;
        }
      __syncthreads();
      if (tid == 0) {
        unsigned ne = s_eqc; if (ne > BCAP) ne = BCAP;
        unsigned mm = (needq < ne) ? needq : ne;
        float es = 0.0f; unsigned ic = 0xffffffffu;
        for (unsigned a = 0; a < mm; ++a) {
          unsigned best = a;
          for (unsigned q = a + 1; q < ne; ++q)
            if (s_eqi[q] < s_eqi[best]) best = q;
          unsigned ti = s_eqi[a]; s_eqi[a] = s_eqi[best]; s_eqi[best] = ti;
          es += lossf(P[s_eqi[a]], 0.0f, M[s_eqi[a]]);
        }
        if (mm > 0) ic = s_eqi[mm - 1];
        s_f = es; s_u1 = ic;
      }
      __syncthreads();
      eq_sum = s_f; idxcut = s_u1;
      __syncthreads();
    }
    if (k >= nsel) {
      float s = 0.0f;
      for (unsigned i = tid; i < NPTS; i += 256) {
        if (T[i] != 0.0f) continue;
        unsigned kk = keyOf(i);
        if (kk < THRESH_KEY) continue;
        if (take_all || kk > V) s += lossf(P[i], 0.0f, M[i]);
      }
      res = redSumF(s) + (take_all ? 0.0f : eq_sum);
    } else {
      auto cLossGe = [&](unsigned w) -> unsigned {
        unsigned c = 0;
        for (unsigned i = tid; i < NPTS; i += 256) {
          if (T[i] != 0.0f) continue;
          unsigned kk = keyOf(i);
          if (kk < THRESH_KEY) continue;
          bool sel = take_all || kk > V || (kk == V && i <= idxcut);
          if (sel && __float_as_uint(lossf(P[i], 0.0f, M[i])) >= w) c++;
        }
        return redSumU(c);
      };
      unsigned lo = 0u, hi = 0x7f7fffffu;
      while (lo < hi) {
        unsigned mid = lo + (hi - lo + 1u) / 2u;
        if (cLossGe(mid) >= k) lo = mid; else hi = mid - 1u;
      }
      unsigned cgt = cLossGe(lo + 1u);
      float s = 0.0f;
      for (unsigned i = tid; i < NPTS; i += 256) {
        if (T[i] != 0.0f) continue;
        unsigned kk = keyOf(i);
        if (kk < THRESH_KEY) continue;
        bool sel = take_all || kk > V || (kk == V && i <= idxcut);
        float L = lossf(P[i], 0.0f, M[i]);
        if (sel && __float_as_uint(L) > lo) s += L;
      }
      res = redSumF(s) + (float)(k - cgt) * __uint_as_float(lo);
    }
  }

  if (tid == 0) *(float*)(line + 256) = res;
}

__global__ void passC(const char* __restrict__ hdr, float* __restrict__ out)
{
  const int lane = threadIdx.x;
  float ps = 0.0f, ns = 0.0f;
  if (lane < BATCH) {
    const char* line = hdr + (size_t)lane * HDRB;
    unsigned np = *(const unsigned*)(line + 4);
    float denom = (np > 0u) ? fmaxf((float)np, 1.0f) : 1.0f;
    ps = (*(const float*)(line + 0)) / denom;
    ns = (*(const float*)(line + 256)) / denom;
  }
#pragma unroll
  for (int s = 8; s > 0; s >>= 1) {
    ps += __shfl_down(ps, s, 64);
    ns += __shfl_down(ns, s, 64);
  }
  if (lane == 0 && blockIdx.x == 0) {
    out[0] = ps / (float)BATCH;
    out[1] = ns / (float)BATCH;
  }
}

extern "C" void kernel_launch(void* const* d_in, const int* in_sizes, int n_in,
                              void* d_out, int out_size, void* d_ws, size_t ws_size,
                              hipStream_t stream)
{
  const float* pred   = (const float*)d_in[0];
  const float* target = (const float*)d_in[1];
  const float* mask   = (const float*)d_in[2];
  float* out = (float*)d_out;

  const size_t HDRSZ = (size_t)BATCH * HDRB;                       // 8192
  const size_t FIXED = HDRSZ + 3 * (size_t)BATCH * WCAP * 4;       // 598016
  if (ws_size < FIXED || out_size < 2) {
    hipMemsetAsync(d_out, 0, sizeof(float) * (out_size > 0 ? out_size : 1), stream);
    return;
  }

  char* ws = (char*)d_ws;
  char*     hdr   = ws;
  unsigned* wkey  = (unsigned*)(ws + HDRSZ);
  unsigned* widx  = wkey + (size_t)BATCH * WCAP;
  float*    wloss = (float*)(widx + (size_t)BATCH * WCAP);

  KeyPairs kp;
  for (unsigned b = 0; b < BATCH; ++b) {
    unsigned o0, o1;
    tf2x32(0u, 42u, 0u, b, o0, o1);
    kp.k[2 * b] = o0; kp.k[2 * b + 1] = o1;
  }

  hipMemsetAsync(hdr, 0, HDRSZ, stream);

  mono<<<dim3(NBLK, BATCH), 256, 0, stream>>>(pred, target, mask, hdr,
                                              wkey, widx, wloss, kp);
  select_k<<<BATCH, 256, 0, stream>>>(pred, target, mask, hdr,
                                      wkey, widx, wloss, kp);
  passC<<<1, 64, 0, stream>>>(hdr, out);
}

// Round 15
// 85.064 us; speedup vs baseline: 1.0779x; 1.0427x over previous
//
#include <hip/hip_runtime.h>
#include <stdint.h>

// DetectionLoss for B=16, N=884736. Output: [cls_pos_loss, cls_neg_loss].
//
// R14: mono at 66.8us = 1870 instr/wave (threefry floor 576) — in-line lossf
// under 56%-activated slots + 4x 256-wide reductions. R15: wave-level work
// COMPACTION: flagged lanes stage (idx|class,key) to LDS (~7 instr/slot);
// post-barrier the ~33 staged elems/block are processed compacted (one lossf
// instance per block), psum/hsum via LDS float atomics (no block reduces).
// Inline overflow path keeps exactness unconditional. select_k absorbs passC
// via device-scope ticket. Selection semantics identical to R6-R14 (absmax 0).

#define BATCH 16
#define NPTS 884736u
#define THRESH_KEY 8266976u    // candidate keys >= this (tail 0.01450)
#define THRESH_W   4232691712u // THRESH_KEY<<9 (raw-word compare)
#define KEYMAX 8388607u
#define KSEL 10000u
// cut0 = 2^23 - KSEL*121632/12822 ~= 8293746 ; margin 8000 ~= 8.5 sigma
#define TLO 8285746u
#define THI 8301746u
#define TLO_W 4242301952u      // TLO<<9
#define HI_W  4250494464u      // (THI+1)<<9 : kw>=HI_W <=> key>THI
#define WCAP 3072u             // global window cap/sample (E~1687, sd 41)
#define LCAP 64                // per-block LDS window staging (E~3.9)
#define SCAP 160               // per-block flagged staging (E~31, Poisson)
#define BCAP 64
#define NBLK 432u              // mono grid.x ; 432*2048 = NPTS
#define EPT 8u
#define HDRB 512               // per-sample header stride

// hdr line (512B/sample): +0 f32 pos_sum, +4 u32 npos (line A)
//   +64 u32 cand_total (B) | +128 u32 n_hi, +132 f32 sum_hi (C)
//   +192 u32 n_win, +196 u32 fail (D) | +256 f32 neg_result (E)
// ticket: hdr + BATCH*HDRB - 4 (sample15 line, unused offset 508)

struct KeyPairs { unsigned k[2 * BATCH]; };

__host__ __device__ __forceinline__ void tf2x32(unsigned k0, unsigned k1,
                                                unsigned x0, unsigned x1,
                                                unsigned& o0, unsigned& o1)
{
  unsigned ks0 = k0, ks1 = k1, ks2 = k0 ^ k1 ^ 0x1BD11BDAu;
  x0 += ks0; x1 += ks1;
#define TF_R(r) { x0 += x1; x1 = __builtin_rotateleft32(x1, r); x1 ^= x0; }
  TF_R(13) TF_R(15) TF_R(26) TF_R(6)
  x0 += ks1; x1 += ks2 + 1u;
  TF_R(17) TF_R(29) TF_R(16) TF_R(24)
  x0 += ks2; x1 += ks0 + 2u;
  TF_R(13) TF_R(15) TF_R(26) TF_R(6)
  x0 += ks0; x1 += ks1 + 3u;
  TF_R(17) TF_R(29) TF_R(16) TF_R(24)
  x0 += ks1; x1 += ks2 + 4u;
  TF_R(13) TF_R(15) TF_R(26) TF_R(6)
  x0 += ks2; x1 += ks0 + 5u;
#undef TF_R
  o0 = x0; o1 = x1;
}

__device__ __forceinline__ float lossf(float x, float t, float m)
{
  float e  = __expf(-x);
  float p  = __fdividef(1.0f, 1.0f + e);
  p = fminf(fmaxf(p, 1e-4f), 1.0f - 1e-4f);
  bool is_pos = (t == 1.0f);
  float alpha = is_pos ? 0.75f : 0.25f;
  float pw = is_pos ? (1.0f - p) : p;
  float soft = __logf(1.0f + __expf(-fabsf(x)));
  float bce = fmaxf(x, 0.0f) - x * t + soft;
  float L = (m == 0.0f) ? alpha * pw * pw * bce : 0.0f;
  if (is_pos && p < 0.8f) L *= 4.0f;
  if (!is_pos && p > 0.5f)
    L *= 1.5f + fminf(fmaxf((p - 0.5f) * 5.0f, 0.0f), 1.0f) * 0.5f;
  return L;
}

__global__ __launch_bounds__(256) void mono(
    const float* __restrict__ pred, const float* __restrict__ target,
    const float* __restrict__ mask, char* __restrict__ hdr,
    unsigned* __restrict__ wkey, unsigned* __restrict__ widx,
    float* __restrict__ wloss, KeyPairs kp)
{
  const int b = blockIdx.y;
  const int tid = threadIdx.x;
  const unsigned i0 = (blockIdx.x * 256u + tid) * EPT;
  const size_t sbase = (size_t)b * NPTS;
  const size_t off = sbase + i0;
  const unsigned k0 = kp.k[2 * b], k1 = kp.k[2 * b + 1];
  char* line = hdr + (size_t)b * HDRB;

  __shared__ unsigned s_n, s_wn, s_base, s_candhi, s_pos;
  __shared__ float    s_psum, s_hsum;
  __shared__ unsigned s_si[SCAP], s_skey[SCAP];
  __shared__ unsigned s_wk[LCAP], s_wi[LCAP];
  __shared__ float    s_wl[LCAP];

  if (tid == 0) {
    s_n = 0; s_wn = 0; s_candhi = 0; s_pos = 0;
    s_psum = 0.0f; s_hsum = 0.0f;
  }
  __syncthreads();

  float4 t4a = *reinterpret_cast<const float4*>(target + off);
  float4 t4b = *reinterpret_cast<const float4*>(target + off + 4);
  float tv[8] = { t4a.x, t4a.y, t4a.z, t4a.w, t4b.x, t4b.y, t4b.z, t4b.w };

  unsigned kw[8];
#pragma unroll
  for (int r = 0; r < 8; ++r) {
    unsigned o0, o1;
    tf2x32(k0, k1, 0u, i0 + (unsigned)r, o0, o1);   // partitionable: (0, i)
    kw[r] = o0 ^ o1;                                 // raw word; key = kw>>9
  }

  unsigned candm = 0, posm = 0, him = 0, winm = 0;
#pragma unroll
  for (int r = 0; r < 8; ++r) {
    bool c  = (tv[r] == 0.0f) && (kw[r] >= THRESH_W);
    bool hi = c && (kw[r] >= HI_W);
    bool wn = c && !hi && (kw[r] >= TLO_W);
    candm |= (unsigned)c  << r;
    him   |= (unsigned)hi << r;
    winm  |= (unsigned)wn << r;
    posm  |= (unsigned)(tv[r] == 1.0f) << r;
  }

  if (candm) atomicAdd(&s_candhi, (unsigned)__popc(candm) | ((unsigned)__popc(him) << 16));
  if (posm)  atomicAdd(&s_pos, (unsigned)__popc(posm));

  // stage flagged elements (idx|class, key); class 0=hi 1=win 2=pos
  const unsigned flags = him | winm | posm;
  if (flags) {
#pragma unroll
    for (int r = 0; r < 8; ++r) {
      if ((flags >> r) & 1u) {
        unsigned cls = ((posm >> r) & 1u) ? 2u : (((winm >> r) & 1u) ? 1u : 0u);
        unsigned p = atomicAdd(&s_n, 1u);
        if (p < SCAP) {
          s_si[p] = (i0 + (unsigned)r) | (cls << 20);
          s_skey[p] = kw[r] >> 9;
        } else {
          // inline overflow path (probability ~0): exact regardless
          float x = pred[off + r], m = mask[off + r];
          float L = lossf(x, (cls == 2u) ? 1.0f : 0.0f, m);
          if (cls == 2u) atomicAdd(&s_psum, L);
          else if (cls == 0u) atomicAdd(&s_hsum, L);
          else {
            unsigned w = atomicAdd(&s_wn, 1u);
            if (w < LCAP) { s_wk[w] = kw[r] >> 9; s_wi[w] = i0 + (unsigned)r; s_wl[w] = L; }
          }
        }
      }
    }
  }
  __syncthreads();

  // compacted processing: ~33 elements/block, one lossf instance per block
  unsigned n = s_n < SCAP ? s_n : SCAP;
  for (unsigned e = tid; e < n; e += 256) {
    unsigned rec = s_si[e];
    unsigned i = rec & 0xFFFFFu, cls = rec >> 20;
    float x = pred[sbase + i], m = mask[sbase + i];
    float L = lossf(x, (cls == 2u) ? 1.0f : 0.0f, m);
    if (cls == 2u) atomicAdd(&s_psum, L);
    else if (cls == 0u) atomicAdd(&s_hsum, L);
    else {
      unsigned w = atomicAdd(&s_wn, 1u);
      if (w < LCAP) { s_wk[w] = s_skey[e]; s_wi[w] = i; s_wl[w] = L; }
    }
  }
  __syncthreads();

  if (tid == 0) {
    unsigned c = s_candhi & 0xFFFFu, h = s_candhi >> 16, p = s_pos;
    if (c) atomicAdd((unsigned*)(line + 64), c);
    if (h) { atomicAdd((unsigned*)(line + 128), h); atomicAdd((float*)(line + 132), s_hsum); }
    if (p) { atomicAdd((unsigned*)(line + 4), p); atomicAdd((float*)(line + 0), s_psum); }
    unsigned wn = s_wn;
    if (wn > LCAP) { atomicOr((unsigned*)(line + 196), 1u); wn = LCAP; }
    s_base = wn ? atomicAdd((unsigned*)(line + 192), wn) : 0u;
    s_wn = wn;
  }
  __syncthreads();
  unsigned wn = s_wn, gb = s_base;
  for (unsigned e = tid; e < wn; e += 256) {
    unsigned g = gb + e;
    if (g < WCAP) {
      wkey[b * WCAP + g] = s_wk[e];
      widx[b * WCAP + g] = s_wi[e];
      wloss[b * WCAP + g] = s_wl[e];
    }
  }
}

// select_k: 16 blocks. Window selection in LDS (normal), full-rescan exact
// fallback (dead). Last block (ticket) computes the final 2-float output.
__global__ __launch_bounds__(256) void select_k(
    const float* __restrict__ pred, const float* __restrict__ target,
    const float* __restrict__ mask, char* __restrict__ hdr,
    const unsigned* __restrict__ wkey, const unsigned* __restrict__ widx,
    const float* __restrict__ wloss, float* __restrict__ out, KeyPairs kp)
{
  const int b = blockIdx.x;
  const int tid = threadIdx.x;
  char* line = hdr + (size_t)b * HDRB;
  unsigned* ticket = (unsigned*)(hdr + (size_t)BATCH * HDRB - 4);

  __shared__ unsigned skey[WCAP], sidx[WCAP];
  __shared__ float    sls[WCAP];
  __shared__ unsigned redu[256];
  __shared__ float    redf[256];
  __shared__ unsigned s_eqc, s_u1, s_tick;
  __shared__ unsigned s_eqi[BCAP];
  __shared__ float    s_eql[BCAP];
  __shared__ float    s_f;

  const unsigned cnt    = *(const unsigned*)(line + 64);
  const unsigned n_hi   = *(const unsigned*)(line + 128);
  const float    sum_hi = *(const float*)(line + 132);
  const unsigned n_win  = *(const unsigned*)(line + 192);
  const unsigned fail   = *(const unsigned*)(line + 196);
  const unsigned npos   = *(const unsigned*)(line + 4);
  const bool take_all = (cnt <= KSEL);
  const unsigned nsel = take_all ? cnt : KSEL;
  const unsigned k = (npos > 0u) ? ((100u * npos < KSEL) ? 100u * npos : KSEL) : 100u;
  const bool bad = fail || take_all || (n_hi > KSEL) ||
                   (n_hi + n_win < KSEL) || (n_win > WCAP) || (k < nsel);

  auto redSumU = [&](unsigned v) -> unsigned {
    redu[tid] = v; __syncthreads();
    for (int s = 128; s > 0; s >>= 1) { if (tid < s) redu[tid] += redu[tid + s]; __syncthreads(); }
    unsigned r = redu[0]; __syncthreads(); return r;
  };
  auto redSumF = [&](float v) -> float {
    redf[tid] = v; __syncthreads();
    for (int s = 128; s > 0; s >>= 1) { if (tid < s) redf[tid] += redf[tid + s]; __syncthreads(); }
    float r = redf[0]; __syncthreads(); return r;
  };

  float res = 0.0f;

  if (!bad) {
    const unsigned nw = n_win;
    for (unsigned e = tid; e < nw; e += 256) {
      skey[e] = wkey[b * WCAP + e];
      sidx[e] = widx[b * WCAP + e];
      sls[e]  = wloss[b * WCAP + e];
    }
    __syncthreads();
    const unsigned need = KSEL - n_hi;
    if (need == 0) res = sum_hi;
    else {
      auto cGe = [&](unsigned v) -> unsigned {
        unsigned c = 0;
        for (unsigned e = tid; e < nw; e += 256) c += (skey[e] >= v) ? 1u : 0u;
        return redSumU(c);
      };
      unsigned lo = TLO, hi = THI;                 // cGe(TLO)=nw>=need
      while (lo < hi) {
        unsigned mid = lo + (hi - lo + 1u) / 2u;
        if (cGe(mid) >= need) lo = mid; else hi = mid - 1u;
      }
      const unsigned V = lo;
      const unsigned c_gt = cGe(V + 1u);
      const unsigned m = need - c_gt;
      float s = 0.0f;
      for (unsigned e = tid; e < nw; e += 256) if (skey[e] > V) s += sls[e];
      float sum_gt = redSumF(s);
      if (tid == 0) s_eqc = 0;
      __syncthreads();
      for (unsigned e = tid; e < nw; e += 256) {
        if (skey[e] == V) {
          unsigned p = atomicAdd(&s_eqc, 1u);
          if (p < BCAP) { s_eqi[p] = sidx[e]; s_eql[p] = sls[e]; }
        }
      }
      __syncthreads();
      if (tid == 0) {
        unsigned ne = s_eqc; if (ne > BCAP) ne = BCAP;
        unsigned mm = (m < ne) ? m : ne;
        float es = 0.0f;
        for (unsigned a = 0; a < mm; ++a) {        // idx asc (LDS only)
          unsigned best = a;
          for (unsigned q = a + 1; q < ne; ++q)
            if (s_eqi[q] < s_eqi[best]) best = q;
          unsigned ti = s_eqi[a]; s_eqi[a] = s_eqi[best]; s_eqi[best] = ti;
          float tl = s_eql[a]; s_eql[a] = s_eql[best]; s_eql[best] = tl;
          es += s_eql[a];
        }
        s_f = sum_hi + sum_gt + es;
      }
      __syncthreads();
      res = s_f;
    }
  } else {
    // ---- exact fallback via full rescans (dead for this data) ----
    const float* T = target + (size_t)b * NPTS;
    const float* P = pred   + (size_t)b * NPTS;
    const float* M = mask   + (size_t)b * NPTS;
    const unsigned k0 = kp.k[2 * b], k1 = kp.k[2 * b + 1];
    auto keyOf = [&](unsigned i) -> unsigned {
      unsigned o0, o1; tf2x32(k0, k1, 0u, i, o0, o1); return (o0 ^ o1) >> 9;
    };
    auto cKeyGe = [&](unsigned v) -> unsigned {
      unsigned c = 0;
      for (unsigned i = tid; i < NPTS; i += 256)
        if (T[i] == 0.0f && keyOf(i) >= v) c++;
      return redSumU(c);
    };
    unsigned V = 0, idxcut = 0xffffffffu; float eq_sum = 0.0f;
    if (!take_all) {
      unsigned lo = THRESH_KEY, hi = KEYMAX;
      while (lo < hi) {
        unsigned mid = lo + (hi - lo + 1u) / 2u;
        if (cKeyGe(mid) >= KSEL) lo = mid; else hi = mid - 1u;
      }
      V = lo;
      unsigned c_gt = cKeyGe(V + 1u);
      unsigned needq = KSEL - c_gt;
      if (tid == 0) s_eqc = 0;
      __syncthreads();
      for (unsigned i = tid; i < NPTS; i += 256)
        if (T[i] == 0.0f && keyOf(i) == V) {
          unsigned p = atomicAdd(&s_eqc, 1u);
          if (p < BCAP) s_eqi[p] = i;
        }
      __syncthreads();
      if (tid == 0) {
        unsigned ne = s_eqc; if (ne > BCAP) ne = BCAP;
        unsigned mm = (needq < ne) ? needq : ne;
        float es = 0.0f; unsigned ic = 0xffffffffu;
        for (unsigned a = 0; a < mm; ++a) {
          unsigned best = a;
          for (unsigned q = a + 1; q < ne; ++q)
            if (s_eqi[q] < s_eqi[best]) best = q;
          unsigned ti = s_eqi[a]; s_eqi[a] = s_eqi[best]; s_eqi[best] = ti;
          es += lossf(P[s_eqi[a]], 0.0f, M[s_eqi[a]]);
        }
        if (mm > 0) ic = s_eqi[mm - 1];
        s_f = es; s_u1 = ic;
      }
      __syncthreads();
      eq_sum = s_f; idxcut = s_u1;
      __syncthreads();
    }
    if (k >= nsel) {
      float s = 0.0f;
      for (unsigned i = tid; i < NPTS; i += 256) {
        if (T[i] != 0.0f) continue;
        unsigned kk = keyOf(i);
        if (kk < THRESH_KEY) continue;
        if (take_all || kk > V) s += lossf(P[i], 0.0f, M[i]);
      }
      res = redSumF(s) + (take_all ? 0.0f : eq_sum);
    } else {
      auto cLossGe = [&](unsigned w) -> unsigned {
        unsigned c = 0;
        for (unsigned i = tid; i < NPTS; i += 256) {
          if (T[i] != 0.0f) continue;
          unsigned kk = keyOf(i);
          if (kk < THRESH_KEY) continue;
          bool sel = take_all || kk > V || (kk == V && i <= idxcut);
          if (sel && __float_as_uint(lossf(P[i], 0.0f, M[i])) >= w) c++;
        }
        return redSumU(c);
      };
      unsigned lo = 0u, hi = 0x7f7fffffu;
      while (lo < hi) {
        unsigned mid = lo + (hi - lo + 1u) / 2u;
        if (cLossGe(mid) >= k) lo = mid; else hi = mid - 1u;
      }
      unsigned cgt = cLossGe(lo + 1u);
      float s = 0.0f;
      for (unsigned i = tid; i < NPTS; i += 256) {
        if (T[i] != 0.0f) continue;
        unsigned kk = keyOf(i);
        if (kk < THRESH_KEY) continue;
        bool sel = take_all || kk > V || (kk == V && i <= idxcut);
        float L = lossf(P[i], 0.0f, M[i]);
        if (sel && __float_as_uint(L) > lo) s += L;
      }
      res = redSumF(s) + (float)(k - cgt) * __uint_as_float(lo);
    }
  }

  // publish result (device-scope) and take a ticket; last block finalizes
  if (tid == 0) {
    atomicExch((float*)(line + 256), res);
    __threadfence();
    s_tick = atomicAdd(ticket, 1u);
  }
  __syncthreads();
  if (s_tick == BATCH - 1) {
    float ps = 0.0f, ns = 0.0f;
    if (tid < BATCH) {
      char* ln = hdr + (size_t)tid * HDRB;
      float pp = atomicAdd((float*)(ln + 0), 0.0f);
      unsigned np = atomicAdd((unsigned*)(ln + 4), 0u);
      float nr = atomicAdd((float*)(ln + 256), 0.0f);
      float denom = (np > 0u) ? fmaxf((float)np, 1.0f) : 1.0f;
      ps = pp / denom;
      ns = nr / denom;
    }
#pragma unroll
    for (int s = 8; s > 0; s >>= 1) {
      ps += __shfl_down(ps, s, 64);
      ns += __shfl_down(ns, s, 64);
    }
    if (tid == 0) {
      out[0] = ps / (float)BATCH;
      out[1] = ns / (float)BATCH;
    }
  }
}

extern "C" void kernel_launch(void* const* d_in, const int* in_sizes, int n_in,
                              void* d_out, int out_size, void* d_ws, size_t ws_size,
                              hipStream_t stream)
{
  const float* pred   = (const float*)d_in[0];
  const float* target = (const float*)d_in[1];
  const float* mask   = (const float*)d_in[2];
  float* out = (float*)d_out;

  const size_t HDRSZ = (size_t)BATCH * HDRB;                       // 8192
  const size_t FIXED = HDRSZ + 3 * (size_t)BATCH * WCAP * 4;       // 598016
  if (ws_size < FIXED || out_size < 2) {
    hipMemsetAsync(d_out, 0, sizeof(float) * (out_size > 0 ? out_size : 1), stream);
    return;
  }

  char* ws = (char*)d_ws;
  char*     hdr   = ws;
  unsigned* wkey  = (unsigned*)(ws + HDRSZ);
  unsigned* widx  = wkey + (size_t)BATCH * WCAP;
  float*    wloss = (float*)(widx + (size_t)BATCH * WCAP);

  KeyPairs kp;
  for (unsigned b = 0; b < BATCH; ++b) {
    unsigned o0, o1;
    tf2x32(0u, 42u, 0u, b, o0, o1);
    kp.k[2 * b] = o0; kp.k[2 * b + 1] = o1;
  }

  hipMemsetAsync(hdr, 0, HDRSZ, stream);   // zeroes counters + ticket

  mono<<<dim3(NBLK, BATCH), 256, 0, stream>>>(pred, target, mask, hdr,
                                              wkey, widx, wloss, kp);
  select_k<<<BATCH, 256, 0, stream>>>(pred, target, mask, hdr,
                                      wkey, widx, wloss, out, kp);
}